// Round 7
// baseline (220.963 us; speedup 1.0000x reference)
//
#include <hip/hip_runtime.h>

#define F_IN 64
#define F_OUT 40
#define QPN 5            // lanes per node: q=0..3 -> u_lo (16B each, one 64B sector), q=4 -> u_hi (16B)
#define LOQ4 4           // uint4 per u_lo row (64 B)

#define PART_BLK 256
#define PART_EPB 8
#define PART_TILE (PART_BLK * PART_EPB)     // 2048 edges per partition block -> 625 blocks
#define BSHIFT 8                            // 256 nodes per bucket
#define BCAP 4096                           // staging slots per bucket (mean 3277, +14 sigma)
#define MAXB 512                            // >= nbk=391

#define WSTRIDE 17                          // W LDS row stride in float4 (bank-conflict-free)
#define NPB 51                              // nodes per block in fused hop3 (51*5=255 threads)

// ---- bf16 helpers (round-to-nearest-even, pack 2 per uint) ----
__device__ inline unsigned pk2(float x, float y) {
    unsigned a = __float_as_uint(x); a = (a + 0x7FFFu + ((a >> 16) & 1u)) >> 16;
    unsigned b = __float_as_uint(y); b = (b + 0x7FFFu + ((b >> 16) & 1u)) >> 16;
    return a | (b << 16);
}
__device__ inline void up2(unsigned u, float& a, float& b) {
    a = __uint_as_float(u << 16); b = __uint_as_float(u & 0xFFFF0000u);
}

#define ACC8(V) do { float b0_, b1_; \
    up2((V).x, b0_, b1_); a0 += b0_; a1 += b1_; \
    up2((V).y, b0_, b1_); a2 += b0_; a3 += b1_; \
    up2((V).z, b0_, b1_); a4 += b0_; a5 += b1_; \
    up2((V).w, b0_, b1_); a6 += b0_; a7 += b1_; } while (0)

// ---------------- phase A: multisplit partition into dst-buckets ----------------
// bucket b staging region: [b*BCAP, ...). record: src(17b) | dstLow(8b)<<17.
__global__ __launch_bounds__(PART_BLK) void partition_kernel(const int* __restrict__ src,
                                                             const int* __restrict__ dst,
                                                             int* __restrict__ bfill,
                                                             unsigned* __restrict__ staging,
                                                             int E, int nbk) {
    __shared__ int hist[MAXB];
    __shared__ int base[MAXB];
    int tid = threadIdx.x;
    for (int b = tid; b < nbk; b += PART_BLK) hist[b] = 0;
    __syncthreads();

    int rank[PART_EPB];
    int bk[PART_EPB];
    unsigned rec[PART_EPB];
    int eb = blockIdx.x * PART_TILE + tid;
#pragma unroll
    for (int k = 0; k < PART_EPB; ++k) {
        int e = eb + k * PART_BLK;
        if (e < E) {
            int r = src[e];
            int c = dst[e];
            int b = c >> BSHIFT;
            bk[k] = b;
            rec[k] = (unsigned)r | ((unsigned)(c & 255) << 17);
            rank[k] = atomicAdd(&hist[b], 1);
        } else {
            bk[k] = -1;
        }
    }
    __syncthreads();
    for (int b = tid; b < nbk; b += PART_BLK) {
        int h = hist[b];
        base[b] = h ? (b * BCAP + atomicAdd(&bfill[b], h)) : 0;
    }
    __syncthreads();
#pragma unroll
    for (int k = 0; k < PART_EPB; ++k) {
        if (bk[k] >= 0) staging[base[bk[k]] + rank[k]] = rec[k];
    }
}

// ---------------- per-bucket finalize: ebase inline + hist -> scan -> rowptr/dinv + CSR scatter
// 512 threads: record scans at 512-wide; 256-bin histogram/scan guarded to tid<256.
__global__ __launch_bounds__(512) void bucket_finalize_kernel(const unsigned* __restrict__ staging,
                                                              const int* __restrict__ bfill,
                                                              int* __restrict__ rowptr,
                                                              float* __restrict__ dinv,
                                                              float* __restrict__ dinv2,
                                                              int* __restrict__ srcs, int n, int E) {
    int b = blockIdx.x;
    __shared__ int h[256];
    __shared__ int cur[256];
    __shared__ int sbase;
    int tid = threadIdx.x;
    if (tid < 256) h[tid] = 0;
    if (tid == 0) sbase = 0;
    __syncthreads();

    // exclusive bucket prefix: sum bfill[0..b-1] (<= 390 ints, trivial)
    int part = 0;
    for (int j = tid; j < b; j += 512) part += bfill[j];
    if (part) atomicAdd(&sbase, part);

    int cnt = bfill[b];
    const unsigned* rec = staging + (size_t)b * BCAP;
    for (int i = tid; i < cnt; i += 512) {
        atomicAdd(&h[rec[i] >> 17], 1);
    }
    __syncthreads();

    int base = sbase;
    int v = (tid < 256) ? h[tid] : 0;
    // inclusive Hillis-Steele scan of h (all 512 threads hit barriers)
    for (int off = 1; off < 256; off <<= 1) {
        int t = (tid >= off && tid < 256) ? h[tid - off] : 0;
        __syncthreads();
        if (tid < 256) h[tid] += t;
        __syncthreads();
    }
    if (tid < 256) {
        int excl = h[tid] - v;
        int node = (b << BSHIFT) | tid;
        if (node < n) {
            rowptr[node] = base + excl;
            float r = rsqrtf((float)v + 1.0f);
            dinv[node] = r;
            dinv2[node] = r * r;
        }
        cur[tid] = base + excl;
    }
    if (b == 0 && tid == 0) rowptr[n] = E;
    __syncthreads();

    // CSR scatter (LDS cursors; writes confined to this bucket's contiguous region)
    for (int i = tid; i < cnt; i += 512) {
        unsigned rv = rec[i];
        int pos = atomicAdd(&cur[rv >> 17], 1);
        srcs[pos] = (int)(rv & 0x1FFFFu);
    }
}

// ---------------- projection u0 = dinv * (x @ W^T), bf16 out (split u_lo/u_hi) --------
// 2 nodes per thread (NB=2), 10 channels (q = t&3): halves W LDS wave-reads.
__global__ __launch_bounds__(256, 4) void proj_kernel(const float* __restrict__ x,
                                                      const float* __restrict__ W,
                                                      const float* __restrict__ dinv,
                                                      unsigned* __restrict__ ulo,
                                                      unsigned* __restrict__ uhi, int n) {
    __shared__ float Ws[F_OUT * WSTRIDE * 4];
    for (int i = threadIdx.x; i < F_OUT * F_IN; i += 256) {
        int c = i >> 6;
        int k = i & 63;
        Ws[c * (WSTRIDE * 4) + k] = W[i];
    }
    __syncthreads();

    int t = blockIdx.x * 256 + threadIdx.x;
    int g = t >> 2;              // node-pair index
    int q = t & 3;
    int n0 = 2 * g;
    if (n0 >= n) return;
    int n1 = n0 + 1;             // N is even -> always valid

    const float4* xp0 = (const float4*)(x + (size_t)n0 * F_IN);
    const float4* xp1 = (const float4*)(x + (size_t)n1 * F_IN);
    const float4* Wq  = (const float4*)Ws + (size_t)(q * 10) * WSTRIDE;

    float acc0[10], acc1[10];
#pragma unroll
    for (int c = 0; c < 10; ++c) { acc0[c] = 0.0f; acc1[c] = 0.0f; }

#pragma unroll 1
    for (int f4 = 0; f4 < F_IN / 4; ++f4) {
        float4 x0 = xp0[f4];
        float4 x1 = xp1[f4];
#pragma unroll
        for (int c = 0; c < 10; ++c) {
            float4 w = Wq[c * WSTRIDE + f4];
            acc0[c] += x0.x * w.x + x0.y * w.y + x0.z * w.z + x0.w * w.w;
            acc1[c] += x1.x * w.x + x1.y * w.y + x1.z * w.z + x1.w * w.w;
        }
    }

    float d0 = dinv[n0];
    float d1 = dinv[n1];
    // uint index idx = q*5+j of the logical 20-uint row: idx<16 -> ulo, else uhi
#pragma unroll
    for (int j = 0; j < 5; ++j) {
        int idx = q * 5 + j;
        unsigned w0 = pk2(d0 * acc0[2 * j], d0 * acc0[2 * j + 1]);
        unsigned w1 = pk2(d1 * acc1[2 * j], d1 * acc1[2 * j + 1]);
        if (idx < 16) {
            ulo[(size_t)n0 * 16 + idx] = w0;
            ulo[(size_t)n1 * 16 + idx] = w1;
        } else {
            uhi[(size_t)n0 * 4 + (idx - 16)] = w0;
            uhi[(size_t)n1 * 4 + (idx - 16)] = w1;
        }
    }
}

// ---------------- pull propagation (bf16 rows, fp32 accum), split u_lo/u_hi ----------
// thread t: node = t/5, q = t%5. q<4 reads u_lo (4 lanes cover one 64B sector -> 1
// sector-miss per gathered row); q==4 reads u_hi (16B packed, 1.6MB -> L2-resident).
__global__ __launch_bounds__(256) void propagate_kernel(const int* __restrict__ rowptr,
                                                        const int* __restrict__ srcs,
                                                        const float* __restrict__ dinv2,
                                                        const unsigned* __restrict__ ulo_c,
                                                        const unsigned* __restrict__ uhi_c,
                                                        unsigned* __restrict__ ulo_n,
                                                        unsigned* __restrict__ uhi_n, int n) {
    int t = blockIdx.x * blockDim.x + threadIdx.x;
    int node = t / QPN;
    int q = t - node * QPN;
    if (node >= n) return;

    int beg = rowptr[node];
    int end = rowptr[node + 1];

    bool hi = (q == 4);
    const uint4* U = hi ? (const uint4*)uhi_c : (const uint4*)ulo_c;
    int sh = hi ? 0 : 2;                 // row stride in uint4: 1 (u_hi) or 4 (u_lo)
    int off = hi ? 0 : q;

    uint4 sv = U[((size_t)node << sh) + off];   // self loop
    float a0, a1, a2, a3, a4, a5, a6, a7;
    up2(sv.x, a0, a1); up2(sv.y, a2, a3); up2(sv.z, a4, a5); up2(sv.w, a6, a7);

    int i = beg;
    for (; i + 3 < end; i += 4) {
        int s0 = srcs[i], s1 = srcs[i + 1], s2 = srcs[i + 2], s3 = srcs[i + 3];
        uint4 v0 = U[((size_t)s0 << sh) + off];
        uint4 v1 = U[((size_t)s1 << sh) + off];
        uint4 v2 = U[((size_t)s2 << sh) + off];
        uint4 v3 = U[((size_t)s3 << sh) + off];
        ACC8(v0); ACC8(v1); ACC8(v2); ACC8(v3);
    }
    for (; i < end; ++i) {
        uint4 v = U[((size_t)srcs[i] << sh) + off];
        ACC8(v);
    }

    float ds = dinv2[node];
    uint4 o;
    o.x = pk2(ds * a0, ds * a1);
    o.y = pk2(ds * a2, ds * a3);
    o.z = pk2(ds * a4, ds * a5);
    o.w = pk2(ds * a6, ds * a7);
    uint4* Un = hi ? (uint4*)uhi_n : (uint4*)ulo_n;
    Un[((size_t)node << sh) + off] = o;
}

// ---------------- fused hop 3 + bias + log_softmax -> fp32 d_out ----------------
__global__ __launch_bounds__(256) void propagate_lsm_kernel(const int* __restrict__ rowptr,
                                                            const int* __restrict__ srcs,
                                                            const float* __restrict__ dinv,
                                                            const unsigned* __restrict__ ulo_c,
                                                            const unsigned* __restrict__ uhi_c,
                                                            const float* __restrict__ bias,
                                                            float* __restrict__ out, int n) {
    __shared__ float red[256];
    int tid = threadIdx.x;
    int gl = tid / QPN;                    // local group 0..50 (tid 255 -> 51, inactive)
    int q  = tid - gl * QPN;
    int node = blockIdx.x * NPB + gl;
    bool active = (gl < NPB) && (node < n);

    float a0 = 0, a1 = 0, a2 = 0, a3 = 0, a4 = 0, a5 = 0, a6 = 0, a7 = 0;
    float dv = 0.0f;
    if (active) {
        int beg = rowptr[node];
        int end = rowptr[node + 1];
        bool hi = (q == 4);
        const uint4* U = hi ? (const uint4*)uhi_c : (const uint4*)ulo_c;
        int sh = hi ? 0 : 2;
        int off = hi ? 0 : q;
        uint4 sv = U[((size_t)node << sh) + off];
        up2(sv.x, a0, a1); up2(sv.y, a2, a3); up2(sv.z, a4, a5); up2(sv.w, a6, a7);
        int i = beg;
        for (; i + 3 < end; i += 4) {
            int s0 = srcs[i], s1 = srcs[i + 1], s2 = srcs[i + 2], s3 = srcs[i + 3];
            uint4 v0 = U[((size_t)s0 << sh) + off];
            uint4 v1 = U[((size_t)s1 << sh) + off];
            uint4 v2 = U[((size_t)s2 << sh) + off];
            uint4 v3 = U[((size_t)s3 << sh) + off];
            ACC8(v0); ACC8(v1); ACC8(v2); ACC8(v3);
        }
        for (; i < end; ++i) {
            uint4 v = U[((size_t)srcs[i] << sh) + off];
            ACC8(v);
        }
        dv = dinv[node];
    }

    // y_j = dv*a_j + bias[q*8+j]
    float y0 = dv * a0 + bias[q * 8 + 0];
    float y1 = dv * a1 + bias[q * 8 + 1];
    float y2 = dv * a2 + bias[q * 8 + 2];
    float y3 = dv * a3 + bias[q * 8 + 3];
    float y4 = dv * a4 + bias[q * 8 + 4];
    float y5 = dv * a5 + bias[q * 8 + 5];
    float y6 = dv * a6 + bias[q * 8 + 6];
    float y7 = dv * a7 + bias[q * 8 + 7];

    float pm = fmaxf(fmaxf(fmaxf(y0, y1), fmaxf(y2, y3)),
                     fmaxf(fmaxf(y4, y5), fmaxf(y6, y7)));
    red[tid] = active ? pm : -1e30f;
    __syncthreads();
    int base = tid - q;
    float mx = fmaxf(fmaxf(fmaxf(red[base], red[base + 1]), fmaxf(red[base + 2], red[base + 3])),
                     red[base + 4]);
    __syncthreads();
    float ps = __expf(y0 - mx) + __expf(y1 - mx) + __expf(y2 - mx) + __expf(y3 - mx)
             + __expf(y4 - mx) + __expf(y5 - mx) + __expf(y6 - mx) + __expf(y7 - mx);
    red[tid] = active ? ps : 0.0f;
    __syncthreads();
    float se = red[base] + red[base + 1] + red[base + 2] + red[base + 3] + red[base + 4];
    float lse = mx + __logf(se);

    if (active) {
        float4* p = (float4*)(out + (size_t)node * F_OUT + q * 8);
        float4 o0, o1;
        o0.x = y0 - lse; o0.y = y1 - lse; o0.z = y2 - lse; o0.w = y3 - lse;
        o1.x = y4 - lse; o1.y = y5 - lse; o1.z = y6 - lse; o1.w = y7 - lse;
        p[0] = o0;
        p[1] = o1;
    }
}

extern "C" void kernel_launch(void* const* d_in, const int* in_sizes, int n_in,
                              void* d_out, int out_size, void* d_ws, size_t ws_size,
                              hipStream_t stream) {
    const float* x  = (const float*)d_in[0];
    const int*   ei = (const int*)d_in[1];
    const float* W  = (const float*)d_in[2];
    const float* b  = (const float*)d_in[3];

    const int N = in_sizes[0] / F_IN;        // 100000
    const int E = in_sizes[1] / 2;           // 1280000
    const int* src = ei;
    const int* dst = ei + E;
    const int nbk = (N + (1 << BSHIFT) - 1) >> BSHIFT;   // 391

    // ---- workspace layout ----
    char* base = (char*)d_ws;
    size_t off = 0;
    auto alloc = [&](size_t bytes) {
        char* p = base + off;
        off = (off + bytes + 255) & ~(size_t)255;
        return p;
    };
    float*    dinv    = (float*)   alloc((size_t)N * 4);
    float*    dinv2   = (float*)   alloc((size_t)N * 4);
    int*      rowptr  = (int*)     alloc((size_t)(N + 1) * 4);
    int*      bfill   = (int*)     alloc((size_t)MAXB * 4);
    unsigned* staging = (unsigned*)alloc((size_t)nbk * BCAP * 4);    // 6.4 MB
    int*      srcs_s  = (int*)     alloc((size_t)E * 4);
    unsigned* uloA    = (unsigned*)alloc((size_t)N * 16 * 4);        // 6.4 MB (64 B rows)
    unsigned* uhiA    = (unsigned*)alloc((size_t)N * 4 * 4);         // 1.6 MB (16 B rows)
    unsigned* uloB    = (unsigned*)alloc((size_t)N * 16 * 4);        // 6.4 MB
    unsigned* uhiB    = (unsigned*)alloc((size_t)N * 4 * 4);         // 1.6 MB
    float*    outp    = (float*)d_out;

    // 1) partition edges into dst-buckets (bfill = counts, memset-initialized)
    hipMemsetAsync(bfill, 0, (size_t)MAXB * 4, stream);
    partition_kernel<<<(E + PART_TILE - 1) / PART_TILE, PART_BLK, 0, stream>>>(
        src, dst, bfill, staging, E, nbk);

    // 2) per-bucket finalize (inline bucket prefix + rowptr/dinv + CSR scatter), 512 thr
    bucket_finalize_kernel<<<nbk, 512, 0, stream>>>(staging, bfill, rowptr,
                                                    dinv, dinv2, srcs_s, N, E);

    // 3) projection u0 = dinv * (x @ W^T) -> bf16 (uloA,uhiA)  (2 nodes/thread)
    proj_kernel<<<((size_t)N * 2 + 255) / 256, 256, 0, stream>>>(x, W, dinv, uloA, uhiA, N);

    // 4) hops 1,2 in bf16 u-space: A -> B -> A
    const int pt = N * QPN;                  // 500k threads
    const int pg = (pt + 255) / 256;
    propagate_kernel<<<pg, 256, 0, stream>>>(rowptr, srcs_s, dinv2, uloA, uhiA, uloB, uhiB, N);
    propagate_kernel<<<pg, 256, 0, stream>>>(rowptr, srcs_s, dinv2, uloB, uhiB, uloA, uhiA, N);

    // 5) fused hop 3 + bias + log_softmax -> d_out (fp32)
    const int fb = (N + NPB - 1) / NPB;      // 1962 blocks
    propagate_lsm_kernel<<<fb, 256, 0, stream>>>(rowptr, srcs_s, dinv, uloA, uhiA, b, outp, N);
}